// Round 5
// baseline (203.221 us; speedup 1.0000x reference)
//
#include <hip/hip_runtime.h>
#include <math.h>

using u16 = unsigned short;
using u32 = unsigned int;

namespace {
constexpr int Hdim = 128;
constexpr int Pn = 50000;
constexpr int Cn = 20000;
constexpr int Bn = 4;
constexpr int NClause = Bn * Cn;   // 80000
constexpr int NRows = Bn * Pn;     // 200000
constexpr int CAP = 64;            // max clauses per variable (mean deg 4.8; P(>=64) ~ e^-150)
}

typedef __attribute__((ext_vector_type(4))) float f32x4;
typedef __attribute__((ext_vector_type(4))) int i32x4;
typedef __attribute__((ext_vector_type(8))) short bf16x8;

static __device__ __forceinline__ float bf2f(u16 v) {
    u32 u = ((u32)v) << 16;
    return __builtin_bit_cast(float, u);
}
static __device__ __forceinline__ u16 f2bf(float f) {
    u32 u = __builtin_bit_cast(u32, f);
    u32 r = u + 0x7FFFu + ((u >> 16) & 1u);
    return (u16)(r >> 16);
}

__global__ void zero_kernel(int* __restrict__ p, int n4) {
    int g = blockIdx.x * blockDim.x + threadIdx.x;
    if (g < n4) ((i32x4*)p)[g] = (i32x4){0, 0, 0, 0};
}

// C = A * B (128x128 fp32, row-major)
__global__ void mm128_kernel(const float* __restrict__ A, const float* __restrict__ Bm,
                             float* __restrict__ out) {
    int o = blockIdx.x, t = threadIdx.x;
    float acc = 0.f;
#pragma unroll 8
    for (int h = 0; h < Hdim; ++h) acc = fmaf(A[o * Hdim + h], Bm[h * Hdim + t], acc);
    out[o * Hdim + t] = acc;
}

// bias_comb = W_cv*(W_ce*b_vc + b_ce) + b_cv
__global__ void fold_bias_kernel(const float* __restrict__ W_ce, const float* __restrict__ b_vc,
                                 const float* __restrict__ b_ce, const float* __restrict__ W_cv,
                                 const float* __restrict__ b_cv, float* __restrict__ bias_comb) {
    __shared__ float b1[Hdim];
    int o = threadIdx.x;
    float acc = b_ce[o];
    for (int h = 0; h < Hdim; ++h) acc = fmaf(W_ce[o * Hdim + h], b_vc[h], acc);
    b1[o] = acc;
    __syncthreads();
    float acc2 = b_cv[o];
    for (int h = 0; h < Hdim; ++h) acc2 = fmaf(W_cv[o * Hdim + h], b1[h], acc2);
    bias_comb[o] = acc2;
}

// src row-major [n][k] fp32 (B^T). Pack into per-lane MFMA B-frag layout:
// dst[((nt*4+ks)*64 + lane)*8 + j] = bf16(src[nt*16 + (lane&15)][ks*32 + (lane>>4)*8 + j])
__global__ void pack_b_kernel(const float* __restrict__ src, u16* __restrict__ dst) {
    int g = blockIdx.x * blockDim.x + threadIdx.x;   // 2048 total
    int lane = g & 63;
    int n = ((g >> 8) * 16) + (lane & 15);
    int k0 = ((g >> 6) & 3) * 32 + (lane >> 4) * 8;
    bf16x8 o;
#pragma unroll
    for (int j = 0; j < 8; ++j) o[j] = (short)f2bf(src[n * Hdim + k0 + j]);
    *(bf16x8*)(dst + (size_t)g * 8) = o;
}

__global__ void convert_kernel(const float* __restrict__ src, u16* __restrict__ dst) {
    int g = blockIdx.x * blockDim.x + threadIdx.x;   // one per 8 floats
    f32x4 a = ((const f32x4*)src)[(size_t)g * 2];
    f32x4 b = ((const f32x4*)src)[(size_t)g * 2 + 1];
    bf16x8 o;
    o[0] = (short)f2bf(a.x); o[1] = (short)f2bf(a.y);
    o[2] = (short)f2bf(a.z); o[3] = (short)f2bf(a.w);
    o[4] = (short)f2bf(b.x); o[5] = (short)f2bf(b.y);
    o[6] = (short)f2bf(b.z); o[7] = (short)f2bf(b.w);
    *(bf16x8*)(dst + (size_t)g * 8) = o;
}

// bucketed CSR: entries[p*CAP + pos] = fid, cursor[p] = degree (first-occurrence dedup)
__global__ void fill_kernel(const int* __restrict__ ci, int* __restrict__ cursor,
                            int* __restrict__ entries) {
    int fid = blockIdx.x * blockDim.x + threadIdx.x;
    if (fid >= NClause) return;
    int i0 = ci[fid * 3 + 0], i1 = ci[fid * 3 + 1], i2 = ci[fid * 3 + 2];
    int pos = atomicAdd(&cursor[i0], 1);
    entries[i0 * CAP + pos] = fid;
    if (i1 != i0) { pos = atomicAdd(&cursor[i1], 1); entries[i1 * CAP + pos] = fid; }
    if (i2 != i0 && i2 != i1) { pos = atomicAdd(&cursor[i2], 1); entries[i2 * CAP + pos] = fid; }
}

// meanG[fid] = (1/3) * sum_k src_row[i_k]   (pure gather, no GEMM)
// batched=1: rows from src[b*Pn + i] (vsb); batched=0: rows from src[i] (msgs)
__global__ __launch_bounds__(256) void cmean_kernel(const int* __restrict__ ci,
                                                    const u16* __restrict__ src,
                                                    u16* __restrict__ meanG, int batched) {
    int tid = threadIdx.x;
    int r = tid >> 4, gt = tid & 15;
    int fid = blockIdx.x * 16 + r;
    int i0 = ci[fid * 3 + 0], i1 = ci[fid * 3 + 1], i2 = ci[fid * 3 + 2];
    const u16* base = src;
    if (batched) base += (size_t)(fid / Cn) * Pn * Hdim;
    int co = gt * 8;
    bf16x8 v0 = *(const bf16x8*)(base + (size_t)i0 * Hdim + co);
    bf16x8 v1 = *(const bf16x8*)(base + (size_t)i1 * Hdim + co);
    bf16x8 v2 = *(const bf16x8*)(base + (size_t)i2 * Hdim + co);
    bf16x8 o;
#pragma unroll
    for (int j = 0; j < 8; ++j)
        o[j] = (short)f2bf((bf2f((u16)v0[j]) + bf2f((u16)v1[j]) + bf2f((u16)v2[j])) * (1.f / 3.f));
    *(bf16x8*)(meanG + (size_t)fid * Hdim + co) = o;
}

// V[p] = (add_base ? V[p] : 0) + (1/deg) * sum over bucket entries of meanG[fid]
__global__ __launch_bounds__(256) void vagg_kernel(const u16* __restrict__ meanG,
                                                   const int* __restrict__ counts,
                                                   const int* __restrict__ entries,
                                                   u16* __restrict__ V, int add_base) {
    int wave = threadIdx.x >> 6, lane = threadIdx.x & 63;
    int p = blockIdx.x * 4 + wave;
    if (p >= Pn) return;
    int deg = counts[p];
    const int* ep = entries + p * CAP;
    float a0 = 0.f, a1 = 0.f;
    for (int e = 0; e < deg; ++e) {
        int cid = ep[e];
        u32 v = *(const u32*)(meanG + (size_t)cid * Hdim + lane * 2);
        a0 += bf2f((u16)(v & 0xffffu));
        a1 += bf2f((u16)(v >> 16));
    }
    if (deg > 0) { float inv = 1.f / (float)deg; a0 *= inv; a1 *= inv; }
    u32* vp = (u32*)(V + (size_t)p * Hdim + lane * 2);
    if (add_base) {
        u32 old = *vp;
        a0 += bf2f((u16)(old & 0xffffu));
        a1 += bf2f((u16)(old >> 16));
    }
    *vp = (u32)f2bf(a0) | ((u32)f2bf(a1) << 16);
}

// msgs[p] = (accum ? msgs[p] : 0) + (deg>0 ? W*V[p] + bias : 0)
__global__ __launch_bounds__(256) void gemm_kernel(const u16* __restrict__ Vin,
                                                   const u16* __restrict__ Bpack,
                                                   const float* __restrict__ bias,
                                                   const int* __restrict__ counts,
                                                   u16* __restrict__ msgs, int accum) {
    __shared__ __align__(16) u16 Atile[64 * 136];
    __shared__ __align__(16) u16 Btile[128 * 128];
    int tid = threadIdx.x;
    int block0 = blockIdx.x * 64;
    {
        const bf16x8* s = (const bf16x8*)Bpack;
        bf16x8* d = (bf16x8*)Btile;
#pragma unroll
        for (int i = 0; i < 8; ++i) d[tid + i * 256] = s[tid + i * 256];
    }
#pragma unroll
    for (int pass = 0; pass < 4; ++pass) {
        int t = pass * 256 + tid;
        int r = t >> 4, seg = t & 15;
        int row = block0 + r;
        bf16x8 o = (bf16x8){0, 0, 0, 0, 0, 0, 0, 0};
        if (row < Pn) o = *(const bf16x8*)(Vin + (size_t)row * Hdim + seg * 8);
        *(bf16x8*)(&Atile[r * 136 + seg * 8]) = o;
    }
    __syncthreads();
    int w = tid >> 6, l = tid & 63;
    int arow = w * 16 + (l & 15);
    int kofs = (l >> 4) * 8;
    f32x4 acc[8];
#pragma unroll
    for (int nt = 0; nt < 8; ++nt) acc[nt] = (f32x4){0.f, 0.f, 0.f, 0.f};
#pragma unroll
    for (int ks = 0; ks < 4; ++ks) {
        bf16x8 af = *(const bf16x8*)(&Atile[arow * 136 + ks * 32 + kofs]);
#pragma unroll
        for (int nt = 0; nt < 8; ++nt) {
            bf16x8 bfr = *(const bf16x8*)(&Btile[((nt * 4 + ks) * 64 + l) * 8]);
            acc[nt] = __builtin_amdgcn_mfma_f32_16x16x32_bf16(af, bfr, acc[nt], 0, 0, 0);
        }
    }
    __syncthreads();
    int crow = w * 16 + (l >> 4) * 4;
    int dg[4];
#pragma unroll
    for (int reg = 0; reg < 4; ++reg) {
        int p = block0 + crow + reg;
        dg[reg] = (p < Pn) ? counts[p] : 0;
    }
#pragma unroll
    for (int nt = 0; nt < 8; ++nt) {
        int col = nt * 16 + (l & 15);
        float bc = bias[col];
#pragma unroll
        for (int reg = 0; reg < 4; ++reg) {
            float val = acc[nt][reg] + bc;
            Atile[(crow + reg) * 136 + col] = f2bf(dg[reg] > 0 ? val : 0.f);
        }
    }
    __syncthreads();
#pragma unroll
    for (int pass = 0; pass < 4; ++pass) {
        int t = pass * 256 + tid;
        int r = t >> 4, seg = t & 15;
        int row = block0 + r;
        if (row < Pn) {
            bf16x8 o = *(const bf16x8*)(&Atile[r * 136 + seg * 8]);
            if (accum) {
                bf16x8 pv = *(const bf16x8*)(msgs + (size_t)row * Hdim + seg * 8);
#pragma unroll
                for (int j = 0; j < 8; ++j)
                    o[j] = (short)f2bf(bf2f((u16)o[j]) + bf2f((u16)pv[j]));
            }
            *(bf16x8*)(msgs + (size_t)row * Hdim + seg * 8) = o;
        }
    }
}

// out[row] = sigmoid( W_s2 . relu( (vsb[row]+msgs[row%Pn]) * W_s1^T + b_s1 ) + b_s2 )
__global__ __launch_bounds__(256) void final_kernel(
    const u16* __restrict__ vsb, const u16* __restrict__ msgs, const u16* __restrict__ Bpack,
    const float* __restrict__ b_s1, const float* __restrict__ W_s2, const float* __restrict__ b_s2,
    float* __restrict__ out) {
    __shared__ __align__(16) u16 Atile[64 * 136];
    __shared__ __align__(16) u16 Btile[128 * 128];
    int tid = threadIdx.x;
    int block0 = blockIdx.x * 64;
    {
        const bf16x8* s = (const bf16x8*)Bpack;
        bf16x8* d = (bf16x8*)Btile;
#pragma unroll
        for (int i = 0; i < 8; ++i) d[tid + i * 256] = s[tid + i * 256];
    }
#pragma unroll
    for (int pass = 0; pass < 4; ++pass) {
        int t = pass * 256 + tid;
        int r = t >> 4, seg = t & 15;
        int row = block0 + r;
        int p = row % Pn;
        int co = seg * 8;
        bf16x8 v = *(const bf16x8*)(vsb + (size_t)row * Hdim + co);
        bf16x8 m = *(const bf16x8*)(msgs + (size_t)p * Hdim + co);
        bf16x8 o;
#pragma unroll
        for (int j = 0; j < 8; ++j) o[j] = (short)f2bf(bf2f((u16)v[j]) + bf2f((u16)m[j]));
        *(bf16x8*)(&Atile[r * 136 + seg * 8]) = o;
    }
    __syncthreads();
    int w = tid >> 6, l = tid & 63;
    int arow = w * 16 + (l & 15);
    int kofs = (l >> 4) * 8;
    f32x4 acc[8];
#pragma unroll
    for (int nt = 0; nt < 8; ++nt) acc[nt] = (f32x4){0.f, 0.f, 0.f, 0.f};
#pragma unroll
    for (int ks = 0; ks < 4; ++ks) {
        bf16x8 af = *(const bf16x8*)(&Atile[arow * 136 + ks * 32 + kofs]);
#pragma unroll
        for (int nt = 0; nt < 8; ++nt) {
            bf16x8 bfr = *(const bf16x8*)(&Btile[((nt * 4 + ks) * 64 + l) * 8]);
            acc[nt] = __builtin_amdgcn_mfma_f32_16x16x32_bf16(af, bfr, acc[nt], 0, 0, 0);
        }
    }
    float part[4] = {0.f, 0.f, 0.f, 0.f};
#pragma unroll
    for (int nt = 0; nt < 8; ++nt) {
        int col = nt * 16 + (l & 15);
        float b1 = b_s1[col], w2 = W_s2[col];
#pragma unroll
        for (int reg = 0; reg < 4; ++reg)
            part[reg] += fmaxf(acc[nt][reg] + b1, 0.f) * w2;
    }
#pragma unroll
    for (int m = 1; m < 16; m <<= 1)
#pragma unroll
        for (int reg = 0; reg < 4; ++reg) part[reg] += __shfl_xor(part[reg], m, 64);
    if ((l & 15) == 0) {
        float lb = b_s2[0];
        int row0 = block0 + w * 16 + (l >> 4) * 4;
#pragma unroll
        for (int reg = 0; reg < 4; ++reg)
            out[row0 + reg] = 1.f / (1.f + expf(-(part[reg] + lb)));
    }
}

extern "C" void kernel_launch(void* const* d_in, const int* in_sizes, int n_in,
                              void* d_out, int out_size, void* d_ws, size_t ws_size,
                              hipStream_t stream) {
    (void)in_sizes; (void)n_in; (void)out_size; (void)ws_size;
    const int* ci = (const int*)d_in[0];
    const float* vs0 = (const float*)d_in[1];
    const float* W_vc = (const float*)d_in[2];
    const float* b_vc = (const float*)d_in[3];
    const float* W_ce = (const float*)d_in[4];
    const float* b_ce = (const float*)d_in[5];
    const float* W_cv = (const float*)d_in[6];
    const float* b_cv = (const float*)d_in[7];
    const float* W_s1 = (const float*)d_in[8];
    const float* b_s1 = (const float*)d_in[9];
    const float* W_s2 = (const float*)d_in[10];
    const float* b_s2 = (const float*)d_in[11];
    float* out = (float*)d_out;

    char* ws = (char*)d_ws;
    size_t off = 0;
    auto alloc = [&](size_t bytes) -> void* {
        off = (off + 255) & ~(size_t)255;
        void* p = ws + off;
        off += bytes;
        return p;
    };
    float* temp1 = (float*)alloc(Hdim * Hdim * 4);
    float* Wcomb = (float*)alloc(Hdim * Hdim * 4);
    float* bias_comb = (float*)alloc(Hdim * 4);
    u16* WcombPack = (u16*)alloc(Hdim * Hdim * 2);
    u16* Ws1Pack = (u16*)alloc(Hdim * Hdim * 2);
    int* cursor = (int*)alloc(Pn * 4);                      // degree per variable
    int* entries = (int*)alloc((size_t)Pn * CAP * 4);       // 12.8 MB bucketed CSR
    u16* meanG = (u16*)alloc((size_t)NClause * Hdim * 2);   // 20.5 MB
    u16* V = (u16*)alloc((size_t)Pn * Hdim * 2);            // 12.8 MB aggregate
    u16* msgs = (u16*)alloc((size_t)Pn * Hdim * 2);         // 12.8 MB
    u16* vsb = (u16*)alloc((size_t)NRows * Hdim * 2);       // 51.2 MB

    // zero cursor (in-graph hipMemsetAsync is slow/unreliable; tiny custom kernel)
    zero_kernel<<<(Pn / 4 + 255) / 256, 256, 0, stream>>>(cursor, Pn / 4);

    // weight fold + pack
    mm128_kernel<<<Hdim, Hdim, 0, stream>>>(W_ce, W_vc, temp1);
    mm128_kernel<<<Hdim, Hdim, 0, stream>>>(W_cv, temp1, Wcomb);
    fold_bias_kernel<<<1, Hdim, 0, stream>>>(W_ce, b_vc, b_ce, W_cv, b_cv, bias_comb);
    pack_b_kernel<<<8, 256, 0, stream>>>(Wcomb, WcombPack);
    pack_b_kernel<<<8, 256, 0, stream>>>(W_s1, Ws1Pack);

    // bf16 copy of variable_states
    convert_kernel<<<(NRows * Hdim / 8) / 256, 256, 0, stream>>>(vs0, vsb);

    // bucketed CSR build
    int nb = (NClause + 255) / 256;
    fill_kernel<<<nb, 256, 0, stream>>>(ci, cursor, entries);

    int gemm_grid = (Pn + 63) / 64;

    // iter 1: V1 = S2*S1*vsb ; msgs1 = mask(W*V1 + bias)
    cmean_kernel<<<NClause / 16, 256, 0, stream>>>(ci, vsb, meanG, 1);
    vagg_kernel<<<(Pn + 3) / 4, 256, 0, stream>>>(meanG, cursor, entries, V, 0);
    gemm_kernel<<<gemm_grid, 256, 0, stream>>>(V, WcombPack, bias_comb, cursor, msgs, 0);

    // iter 2: V = V1 + S2*S1*msgs1 ; msgs2 = msgs1 + mask(W*V + bias)
    cmean_kernel<<<NClause / 16, 256, 0, stream>>>(ci, msgs, meanG, 0);
    vagg_kernel<<<(Pn + 3) / 4, 256, 0, stream>>>(meanG, cursor, entries, V, 1);
    gemm_kernel<<<gemm_grid, 256, 0, stream>>>(V, WcombPack, bias_comb, cursor, msgs, 1);

    final_kernel<<<NRows / 64, 256, 0, stream>>>(vsb, msgs, Ws1Pack, b_s1, W_s2, b_s2, out);
}